// Round 17
// baseline (533.823 us; speedup 1.0000x reference)
//
#include <hip/hip_runtime.h>
#include <math.h>

#define NT_NODES 30000
#define NE_EDGES 200000
#define NTY 3
#define NRL 4
#define NLY 2
#define NH 8
#define HD 16
#define FDIM 128
#define SCAN_BLOCKS 118   // ceil(30000/256)

typedef unsigned short u16;
typedef unsigned int u32;
typedef __attribute__((ext_vector_type(8))) short bf16x8;
typedef __attribute__((ext_vector_type(4))) float f32x4;

__device__ __forceinline__ float bf2f(u16 u) {
  return __uint_as_float(((u32)u) << 16);
}
__device__ __forceinline__ u16 f2bf(float f) {   // RNE
  u32 u = __float_as_uint(f);
  return (u16)((u + 0x7FFFu + ((u >> 16) & 1u)) >> 16);
}

__device__ __forceinline__ float gelu_f(float x) {
  return 0.5f * x * (1.f + erff(x * 0.7071067811865475f));
}

// -------------------------------------------------- weight prep (bf16 W^T) --
// 23 matrices: [0..13] QKV (7/layer; q entries 0..2 unused now), [14..16]
// lin_w, [17..22] a_w
struct WtBatch { const float* w[23]; };
__global__ __launch_bounds__(256) void wt_prep(WtBatch wb, u16* wt) {
  const float* w = wb.w[blockIdx.x];
  u16* o = wt + (size_t)blockIdx.x * FDIM * FDIM;
  for (int i = threadIdx.x; i < FDIM * FDIM; i += 256) {
    int n = i >> 7, k = i & 127;            // o[n][k] = w[k][n]
    o[i] = f2bf(w[(size_t)k * FDIM + n]);
  }
}

// ---- fused Q' weights: per (layer, rel) WT'[n=h*16+cl][k] =
//      s_h * sum_ee A_rel[h][cl][ee] * q_w[dst(r)][k][h*16+ee],
//      bias'[n] likewise. s_h = prel[h]/4.
__global__ __launch_bounds__(256) void qfuse(const float* __restrict__ q_w,
                                             const float* __restrict__ q_b,
                                             const float* __restrict__ a_rel,
                                             const float* __restrict__ p_rel,
                                             u16* __restrict__ wqp,
                                             float* __restrict__ bqp) {
  const int lr = blockIdx.x;            // 0..7 = l*4+r
  const int l = lr >> 2, r = lr & 3;
  const int dt = (r == 1) ? 1 : ((r == 3) ? 2 : 0);   // EDST
  const float* qw = q_w + (size_t)(l * NTY + dt) * FDIM * FDIM;
  const float* qb = q_b + (size_t)(l * NTY + dt) * FDIM;
  const float* A  = a_rel + (size_t)(l * NRL + r) * NH * HD * HD;
  const float* pr = p_rel + (size_t)(l * NRL + r) * NH;
  u16* wo = wqp + (size_t)lr * FDIM * FDIM;
  float* bo = bqp + (size_t)lr * FDIM;

  __shared__ float As[NH * HD * HD];   // 8KB
  __shared__ float sh[NH];
  for (int i = threadIdx.x; i < NH * HD * HD; i += 256) As[i] = A[i];
  if (threadIdx.x < NH) sh[threadIdx.x] = pr[threadIdx.x] * 0.25f;
  __syncthreads();

  for (int i = threadIdx.x; i < FDIM * FDIM; i += 256) {
    int n = i >> 7, k = i & 127;
    int h = n >> 4, cl = n & 15;
    float s = 0.f;
    #pragma unroll
    for (int ee = 0; ee < HD; ee++)
      s += qw[(size_t)k * FDIM + h * HD + ee] * As[h * HD * HD + cl * HD + ee];
    wo[(size_t)n * FDIM + k] = f2bf(s * sh[h]);
  }
  if (threadIdx.x < FDIM) {
    int n = threadIdx.x, h = n >> 4, cl = n & 15;
    float s = 0.f;
    #pragma unroll
    for (int ee = 0; ee < HD; ee++)
      s += qb[h * HD + ee] * As[h * HD * HD + cl * HD + ee];
    bo[n] = s * sh[h];
  }
}

// ------------------------------------------------------- MFMA core ----------
// Block: 256 thr (4 waves), tile 64 rows; wave w -> cols 32w..32w+31.
// LDS XOR-swizzle on 16B granules: granule k8 stored at k8 ^ (row&7).
// C/D layout: col=lane&15, row=(lane>>4)*4+rr (verified R9).

// --- fused QKV: A (bf16 h) staged once, MFMA A-fragments in registers.
// 4 z-slices balanced to <=3 matmul passes each.
struct QkvOut { const u16* WT; const float* bias; u16* C; };
struct QkvTask {
  const u16* A; int nplain; QkvOut o[2];
  int haskv; const u16* WTk; const float* biask; const u16* WTv; const float* biasv; u32* Ckv;
};
struct QkvBatch { QkvTask t[4]; };

__global__ __launch_bounds__(256) void gemm_qkv(QkvBatch gb, int M) {
  const QkvTask tk = gb.t[blockIdx.z];
  const int tid = threadIdx.x;
  const int wv = tid >> 6;
  const int lane = tid & 63;
  const int row0 = blockIdx.x * 64;

  __shared__ u16 As[64 * 128];
  __shared__ u16 Bt[128 * 128];

  // stage A (bf16 direct copy, swizzled granules)
  #pragma unroll
  for (int i = 0; i < 4; i++) {
    int g = tid + 256 * i;
    int r = g >> 4, k8 = g & 15;
    int grow = row0 + r;
    uint4 v = make_uint4(0, 0, 0, 0);
    if (grow < M) v = *(const uint4*)(tk.A + (size_t)grow * FDIM + k8 * 8);
    *(uint4*)(As + r * 128 + ((k8 ^ (r & 7)) * 8)) = v;
  }
  __syncthreads();

  const int rsel = lane & 15, ksel = lane >> 4;
  // A-fragments in registers, reused for all outputs
  bf16x8 af[4][4];
  #pragma unroll
  for (int ks = 0; ks < 4; ks++) {
    int kg = ks * 4 + ksel;
    #pragma unroll
    for (int i = 0; i < 4; i++) {
      int r = 16 * i + rsel;
      af[ks][i] = *(const bf16x8*)(As + r * 128 + ((kg ^ (r & 7)) * 8));
    }
  }

  // ---- plain outputs (Q' tables, contiguous u16 writes) ----
  for (int ot = 0; ot < tk.nplain; ot++) {
    const QkvOut oo = tk.o[ot];
    #pragma unroll
    for (int i = 0; i < 8; i++) {
      int g = tid + 256 * i;
      int n = g >> 4, k8 = g & 15;
      uint4 v = *(const uint4*)(oo.WT + (size_t)n * FDIM + k8 * 8);
      *(uint4*)(Bt + n * 128 + ((k8 ^ (n & 7)) * 8)) = v;
    }
    __syncthreads();

    f32x4 acc[4][2] = {};
    #pragma unroll
    for (int ks = 0; ks < 4; ks++) {
      int kg = ks * 4 + ksel;
      bf16x8 bfr[2];
      #pragma unroll
      for (int j = 0; j < 2; j++) {
        int n = 32 * wv + 16 * j + rsel;
        bfr[j] = *(const bf16x8*)(Bt + n * 128 + ((kg ^ (n & 7)) * 8));
      }
      #pragma unroll
      for (int i = 0; i < 4; i++)
        #pragma unroll
        for (int j = 0; j < 2; j++)
          acc[i][j] = __builtin_amdgcn_mfma_f32_16x16x32_bf16(af[ks][i], bfr[j], acc[i][j], 0, 0, 0);
    }

    float bj[2];
    int colj[2];
    #pragma unroll
    for (int j = 0; j < 2; j++) {
      colj[j] = 32 * wv + 16 * j + rsel;
      bj[j] = oo.bias[colj[j]];
    }
    #pragma unroll
    for (int i = 0; i < 4; i++) {
      #pragma unroll
      for (int rr = 0; rr < 4; rr++) {
        int grow = row0 + 16 * i + (lane >> 4) * 4 + rr;
        if (grow >= M) continue;
        #pragma unroll
        for (int j = 0; j < 2; j++)
          oo.C[(size_t)grow * FDIM + colj[j]] = f2bf(acc[i][j][rr] + bj[j]);
      }
    }
    __syncthreads();
  }

  // ---- KV pair: K-pass acc held in regs, V-pass, then coalesced u32 write --
  if (tk.haskv) {
    // K pass
    #pragma unroll
    for (int i = 0; i < 8; i++) {
      int g = tid + 256 * i;
      int n = g >> 4, k8 = g & 15;
      uint4 v = *(const uint4*)(tk.WTk + (size_t)n * FDIM + k8 * 8);
      *(uint4*)(Bt + n * 128 + ((k8 ^ (n & 7)) * 8)) = v;
    }
    __syncthreads();
    f32x4 accK[4][2] = {};
    #pragma unroll
    for (int ks = 0; ks < 4; ks++) {
      int kg = ks * 4 + ksel;
      bf16x8 bfr[2];
      #pragma unroll
      for (int j = 0; j < 2; j++) {
        int n = 32 * wv + 16 * j + rsel;
        bfr[j] = *(const bf16x8*)(Bt + n * 128 + ((kg ^ (n & 7)) * 8));
      }
      #pragma unroll
      for (int i = 0; i < 4; i++)
        #pragma unroll
        for (int j = 0; j < 2; j++)
          accK[i][j] = __builtin_amdgcn_mfma_f32_16x16x32_bf16(af[ks][i], bfr[j], accK[i][j], 0, 0, 0);
    }
    __syncthreads();
    // V pass
    #pragma unroll
    for (int i = 0; i < 8; i++) {
      int g = tid + 256 * i;
      int n = g >> 4, k8 = g & 15;
      uint4 v = *(const uint4*)(tk.WTv + (size_t)n * FDIM + k8 * 8);
      *(uint4*)(Bt + n * 128 + ((k8 ^ (n & 7)) * 8)) = v;
    }
    __syncthreads();
    f32x4 accV[4][2] = {};
    #pragma unroll
    for (int ks = 0; ks < 4; ks++) {
      int kg = ks * 4 + ksel;
      bf16x8 bfr[2];
      #pragma unroll
      for (int j = 0; j < 2; j++) {
        int n = 32 * wv + 16 * j + rsel;
        bfr[j] = *(const bf16x8*)(Bt + n * 128 + ((kg ^ (n & 7)) * 8));
      }
      #pragma unroll
      for (int i = 0; i < 4; i++)
        #pragma unroll
        for (int j = 0; j < 2; j++)
          accV[i][j] = __builtin_amdgcn_mfma_f32_16x16x32_bf16(af[ks][i], bfr[j], accV[i][j], 0, 0, 0);
    }

    float bk[2], bv[2];
    int colj[2];
    #pragma unroll
    for (int j = 0; j < 2; j++) {
      colj[j] = 32 * wv + 16 * j + rsel;
      bk[j] = tk.biask[colj[j]];
      bv[j] = tk.biasv[colj[j]];
    }
    #pragma unroll
    for (int i = 0; i < 4; i++) {
      #pragma unroll
      for (int rr = 0; rr < 4; rr++) {
        int grow = row0 + 16 * i + (lane >> 4) * 4 + rr;
        if (grow >= M) continue;
        #pragma unroll
        for (int j = 0; j < 2; j++) {
          u32 pk = (u32)f2bf(accK[i][j][rr] + bk[j]);
          u32 pv = (u32)f2bf(accV[i][j][rr] + bv[j]);
          tk.Ckv[(size_t)grow * FDIM + colj[j]] = pk | (pv << 16);
        }
      }
    }
  }
}

// --- general MFMA GEMM. A may be f32 or bf16 (BF16_A); oldh is bf16.
struct GemmTaskF {
  const float* A; const float* A2; const u16* WT; const float* bias;
  float* C; const u16* oldh; const float* skipp;
};
struct GemmBatchF { GemmTaskF t[3]; };

template<int GELU_A, int EPI_SKIP, int RELU, int BF16_OUT, int BF16_A>
__global__ __launch_bounds__(256) void gemm_mfma_f(GemmBatchF gb, int M) {
  const GemmTaskF tk = gb.t[blockIdx.z];
  const int tid = threadIdx.x;
  const int wv = tid >> 6;
  const int lane = tid & 63;
  const int row0 = blockIdx.x * 64;

  __shared__ u16 As[64 * 128];
  __shared__ u16 Bt[128 * 128];

  #pragma unroll
  for (int i = 0; i < 4; i++) {
    int g = tid + 256 * i;
    int r = g >> 4, k8 = g & 15;
    int grow = row0 + r;
    if (BF16_A) {
      uint4 v = make_uint4(0, 0, 0, 0);
      if (grow < M) {
        v = *(const uint4*)((const u16*)tk.A + (size_t)grow * FDIM + k8 * 8);
        if (GELU_A) {
          uint4 v2 = make_uint4(0, 0, 0, 0);
          if (tk.A2) v2 = *(const uint4*)((const u16*)tk.A2 + (size_t)grow * FDIM + k8 * 8);
          u32 vv[4] = {v.x, v.y, v.z, v.w};
          u32 ww[4] = {v2.x, v2.y, v2.z, v2.w};
          #pragma unroll
          for (int q = 0; q < 4; q++) {
            float lo = __uint_as_float(vv[q] << 16);
            float hi = __uint_as_float(vv[q] & 0xFFFF0000u);
            if (tk.A2) {
              lo += __uint_as_float(ww[q] << 16);
              hi += __uint_as_float(ww[q] & 0xFFFF0000u);
            }
            lo = gelu_f(lo); hi = gelu_f(hi);
            vv[q] = (u32)f2bf(lo) | ((u32)f2bf(hi) << 16);
          }
          v = make_uint4(vv[0], vv[1], vv[2], vv[3]);
        }
      }
      *(uint4*)(As + r * 128 + ((k8 ^ (r & 7)) * 8)) = v;
    } else {
      float4 va = make_float4(0.f, 0.f, 0.f, 0.f), vb = va;
      if (grow < M) {
        const float* ap = tk.A + (size_t)grow * FDIM + k8 * 8;
        va = *(const float4*)ap;
        vb = *(const float4*)(ap + 4);
        if (GELU_A) {
          va.x = gelu_f(va.x); va.y = gelu_f(va.y); va.z = gelu_f(va.z); va.w = gelu_f(va.w);
          vb.x = gelu_f(vb.x); vb.y = gelu_f(vb.y); vb.z = gelu_f(vb.z); vb.w = gelu_f(vb.w);
        }
      }
      u32 w0 = (u32)f2bf(va.x) | ((u32)f2bf(va.y) << 16);
      u32 w1 = (u32)f2bf(va.z) | ((u32)f2bf(va.w) << 16);
      u32 w2 = (u32)f2bf(vb.x) | ((u32)f2bf(vb.y) << 16);
      u32 w3 = (u32)f2bf(vb.z) | ((u32)f2bf(vb.w) << 16);
      u32* dst = (u32*)(As + r * 128 + ((k8 ^ (r & 7)) * 8));
      dst[0] = w0; dst[1] = w1; dst[2] = w2; dst[3] = w3;
    }
  }
  #pragma unroll
  for (int i = 0; i < 8; i++) {
    int g = tid + 256 * i;
    int n = g >> 4, k8 = g & 15;
    uint4 v = *(const uint4*)(tk.WT + (size_t)n * FDIM + k8 * 8);
    *(uint4*)(Bt + n * 128 + ((k8 ^ (n & 7)) * 8)) = v;
  }
  __syncthreads();

  f32x4 acc[4][2] = {};
  const int rsel = lane & 15, ksel = lane >> 4;
  #pragma unroll
  for (int ks = 0; ks < 4; ks++) {
    int kg = ks * 4 + ksel;
    bf16x8 af[4], bfr[2];
    #pragma unroll
    for (int i = 0; i < 4; i++) {
      int r = 16 * i + rsel;
      af[i] = *(const bf16x8*)(As + r * 128 + ((kg ^ (r & 7)) * 8));
    }
    #pragma unroll
    for (int j = 0; j < 2; j++) {
      int n = 32 * wv + 16 * j + rsel;
      bfr[j] = *(const bf16x8*)(Bt + n * 128 + ((kg ^ (n & 7)) * 8));
    }
    #pragma unroll
    for (int i = 0; i < 4; i++)
      #pragma unroll
      for (int j = 0; j < 2; j++)
        acc[i][j] = __builtin_amdgcn_mfma_f32_16x16x32_bf16(af[i], bfr[j], acc[i][j], 0, 0, 0);
  }

  float a_s = 0.f, b_s = 0.f;
  if (EPI_SKIP) { a_s = 1.f / (1.f + expf(-tk.skipp[0])); b_s = 1.f - a_s; }
  float bj[2];
  int colj[2];
  #pragma unroll
  for (int j = 0; j < 2; j++) {
    colj[j] = 32 * wv + 16 * j + rsel;
    bj[j] = tk.bias[colj[j]];
  }
  #pragma unroll
  for (int i = 0; i < 4; i++) {
    #pragma unroll
    for (int rr = 0; rr < 4; rr++) {
      int grow = row0 + 16 * i + (lane >> 4) * 4 + rr;
      if (grow >= M) continue;
      #pragma unroll
      for (int j = 0; j < 2; j++) {
        float v = acc[i][j][rr] + bj[j];
        if (RELU) v = fmaxf(v, 0.f);
        if (EPI_SKIP) v = a_s * v + b_s * bf2f(tk.oldh[(size_t)grow * FDIM + colj[j]]);
        if (BF16_OUT) ((u16*)tk.C)[(size_t)grow * FDIM + colj[j]] = f2bf(v);
        else tk.C[(size_t)grow * FDIM + colj[j]] = v;
      }
    }
  }
}

// ------------------------------------------------------------- CSR build ----
__global__ __launch_bounds__(256) void csr_hist(const int* __restrict__ edge_index,
                                                int* __restrict__ counts) {
  int idx = blockIdx.x * 256 + threadIdx.x;
  if (idx >= NRL * NE_EDGES) return;
  int r = idx / NE_EDGES, e = idx - r * NE_EDGES;
  int d = edge_index[(size_t)(r * 2 + 1) * NE_EDGES + e];
  atomicAdd(&counts[r * NT_NODES + d], 1);
}

__global__ __launch_bounds__(256) void scan_block(const int* __restrict__ counts,
                                                  int* __restrict__ off,
                                                  int* __restrict__ aux) {
  int r = blockIdx.y, b = blockIdx.x, t = threadIdx.x;
  int i = b * 256 + t;
  int v = (i < NT_NODES) ? counts[r * NT_NODES + i] : 0;
  __shared__ int lds[256];
  lds[t] = v;
  __syncthreads();
  #pragma unroll
  for (int dlt = 1; dlt < 256; dlt <<= 1) {
    int x = (t >= dlt) ? lds[t - dlt] : 0;
    __syncthreads();
    lds[t] += x;
    __syncthreads();
  }
  if (i < NT_NODES) off[(size_t)r * (NT_NODES + 1) + i] = lds[t] - v;
  if (t == 255) aux[r * SCAN_BLOCKS + b] = lds[255];
}

__global__ __launch_bounds__(128) void scan_aux(const int* __restrict__ aux,
                                                int* __restrict__ auxe,
                                                int* __restrict__ off) {
  int r = blockIdx.x, t = threadIdx.x;
  __shared__ int lds[128];
  int v = (t < SCAN_BLOCKS) ? aux[r * SCAN_BLOCKS + t] : 0;
  lds[t] = v;
  __syncthreads();
  #pragma unroll
  for (int dlt = 1; dlt < 128; dlt <<= 1) {
    int x = (t >= dlt) ? lds[t - dlt] : 0;
    __syncthreads();
    lds[t] += x;
    __syncthreads();
  }
  if (t < SCAN_BLOCKS) auxe[r * SCAN_BLOCKS + t] = lds[t] - v;
  if (t == 127) off[(size_t)r * (NT_NODES + 1) + NT_NODES] = lds[127];
}

__global__ __launch_bounds__(256) void scan_add(const int* __restrict__ auxe,
                                                int* __restrict__ off,
                                                int* __restrict__ cursor) {
  int r = blockIdx.y, b = blockIdx.x, t = threadIdx.x;
  int i = b * 256 + t;
  if (i >= NT_NODES) return;
  int val = off[(size_t)r * (NT_NODES + 1) + i] + auxe[r * SCAN_BLOCKS + b];
  off[(size_t)r * (NT_NODES + 1) + i] = val;
  cursor[r * NT_NODES + i] = val;
}

__global__ __launch_bounds__(256) void csr_scatter(const int* __restrict__ edge_index,
                                                   int* __restrict__ cursor,
                                                   int* __restrict__ csr_src) {
  int idx = blockIdx.x * 256 + threadIdx.x;
  if (idx >= NRL * NE_EDGES) return;
  int r = idx / NE_EDGES, e = idx - r * NE_EDGES;
  int s = edge_index[(size_t)(r * 2 + 0) * NE_EDGES + e];
  int d = edge_index[(size_t)(r * 2 + 1) * NE_EDGES + e];
  int pos = atomicAdd(&cursor[r * NT_NODES + d], 1);
  csr_src[(size_t)r * NE_EDGES + pos] = s;
}

__global__ void csr_pad(int* __restrict__ pad) {
  if (threadIdx.x < 8) pad[threadIdx.x] = 0;
}

// ---------------------------------------------------- fused attention -------
// HEAD-SPLIT + PRE-FUSED Q' + PAIR-INTERLEAVED KV (R16 structure). agg is
// now bf16 (one-touch stream; out-GEMM re-reads it bf16).
struct AttnRel {
  const int* csr_src; const int* off;
  const u16* q;        // bf16 Q' of this relation [N,128] (pre-transformed)
  const u16* kv;       // bf16 KV pair-interleaved [N,256]: K[c] low, V[c] high
  const float* Mrel;   // [8][16][16]
  u16* agg;            // bf16 output [N,128] (overwritten)
};
struct AttnBatch { AttnRel r[4]; };

__global__ __launch_bounds__(256) void attn_fused(AttnBatch ab) {
  const AttnRel rp = ab.r[blockIdx.y];
  const int wave = threadIdx.x >> 6;
  const int lane = threadIdx.x & 63;
  const int d = blockIdx.x * 2 + (wave >> 1);
  if (d >= NT_NODES) return;
  const int hf = wave & 1;              // half: channels hf*64 .. hf*64+63
  const int cl = lane & 15;             // channel within head
  const int gh = hf * 4 + (lane >> 4);  // global head 0..7
  const int grp = lane & ~15;           // 16-lane head group base
  const int el = lane & 7;              // edge slot in transposed reduce

  // ---- Q' already includes A_rel and p/4: direct load ----
  float qp = bf2f(rp.q[(size_t)d * FDIM + hf * 64 + lane]);

  const u32* KV = (const u32*)rp.kv;    // [N][128] u32 (K,V) pairs
  const int* __restrict__ cs = rp.csr_src;
  int lo = rp.off[d], hi = rp.off[d + 1];
  lo = __builtin_amdgcn_readfirstlane(lo);
  hi = __builtin_amdgcn_readfirstlane(hi);
  const size_t poff = hf * 64 + lane;   // u32 pair index within row
  float acc = 0.f, ssum = 0.f;
  for (int pos = lo; pos < hi; pos += 8) {
    int s0 = cs[pos + 0], s1 = cs[pos + 1], s2 = cs[pos + 2], s3 = cs[pos + 3];
    int s4 = cs[pos + 4], s5 = cs[pos + 5], s6 = cs[pos + 6], s7 = cs[pos + 7];
    u32 w0 = KV[(size_t)s0 * 128 + poff], w1 = KV[(size_t)s1 * 128 + poff];
    u32 w2 = KV[(size_t)s2 * 128 + poff], w3 = KV[(size_t)s3 * 128 + poff];
    u32 w4 = KV[(size_t)s4 * 128 + poff], w5 = KV[(size_t)s5 * 128 + poff];
    u32 w6 = KV[(size_t)s6 * 128 + poff], w7 = KV[(size_t)s7 * 128 + poff];
    float p0 = qp * __uint_as_float(w0 << 16), p1 = qp * __uint_as_float(w1 << 16);
    float p2 = qp * __uint_as_float(w2 << 16), p3 = qp * __uint_as_float(w3 << 16);
    float p4 = qp * __uint_as_float(w4 << 16), p5 = qp * __uint_as_float(w5 << 16);
    float p6 = qp * __uint_as_float(w6 << 16), p7 = qp * __uint_as_float(w7 << 16);
    // transposed butterfly over 8 lanes, then fold the other 8 of the head
    float s01 = (lane & 1) ? p0 : p1, c01 = (lane & 1) ? p1 : p0;
    float s23 = (lane & 1) ? p2 : p3, c23 = (lane & 1) ? p3 : p2;
    float s45 = (lane & 1) ? p4 : p5, c45 = (lane & 1) ? p5 : p4;
    float s67 = (lane & 1) ? p6 : p7, c67 = (lane & 1) ? p7 : p6;
    float r01 = c01 + __shfl_xor(s01, 1, 64);
    float r23 = c23 + __shfl_xor(s23, 1, 64);
    float r45 = c45 + __shfl_xor(s45, 1, 64);
    float r67 = c67 + __shfl_xor(s67, 1, 64);
    float sA = (lane & 2) ? r01 : r23, cA = (lane & 2) ? r23 : r01;
    float sB = (lane & 2) ? r45 : r67, cB = (lane & 2) ? r67 : r45;
    float rA = cA + __shfl_xor(sA, 2, 64);
    float rB = cB + __shfl_xor(sB, 2, 64);
    float sC = (lane & 4) ? rA : rB, cC = (lane & 4) ? rB : rA;
    float rF = cC + __shfl_xor(sC, 4, 64);
    rF += __shfl_xor(rF, 8, 64);     // fold remaining 8 lanes of the head
    int rem = hi - pos;              // scalar
    float e = (el < rem) ? __expf(rF) : 0.f;
    float e0 = __shfl(e, grp + 0, 64), e1 = __shfl(e, grp + 1, 64);
    float e2 = __shfl(e, grp + 2, 64), e3 = __shfl(e, grp + 3, 64);
    float e4 = __shfl(e, grp + 4, 64), e5 = __shfl(e, grp + 5, 64);
    float e6 = __shfl(e, grp + 6, 64), e7 = __shfl(e, grp + 7, 64);
    acc += e0 * __uint_as_float(w0 & 0xFFFF0000u) + e1 * __uint_as_float(w1 & 0xFFFF0000u)
         + e2 * __uint_as_float(w2 & 0xFFFF0000u) + e3 * __uint_as_float(w3 & 0xFFFF0000u)
         + e4 * __uint_as_float(w4 & 0xFFFF0000u) + e5 * __uint_as_float(w5 & 0xFFFF0000u)
         + e6 * __uint_as_float(w6 & 0xFFFF0000u) + e7 * __uint_as_float(w7 & 0xFFFF0000u);
    ssum += ((e0 + e1) + (e2 + e3)) + ((e4 + e5) + (e6 + e7));
  }
  float inv = 1.f / (ssum + 1e-16f);
  float S = acc * inv;   // lane's channel of the raw-V aggregate

  // ---- apply M_rel: out_cl = sum_d2 S[d2] * M[gh][d2][cl] ----
  const float* M = rp.Mrel + (size_t)gh * 256;
  float o = 0.f;
  #pragma unroll
  for (int d2 = 0; d2 < 16; d2++) {
    float sv = __shfl(S, grp + d2, 64);
    o += sv * M[d2 * 16 + cl];
  }
  rp.agg[(size_t)d * FDIM + hf * 64 + lane] = f2bf(o);
}

// ---------------------------------------------------------------- scatter ---
__global__ __launch_bounds__(256) void scatter_out(const float* h0, const float* h1,
                                                   const float* h2, const int* ntype,
                                                   float* out, int NN) {
  int idx = blockIdx.x * 256 + threadIdx.x;
  if (idx >= NN * 32) return;
  int i = idx >> 5, c4 = idx & 31;
  int t = ntype[i];
  const float* hp = (t == 0) ? h0 : ((t == 1) ? h1 : h2);
  int local = i - t * NT_NODES;
  ((float4*)out)[idx] = ((const float4*)hp)[(size_t)local * 32 + c4];
}

// ------------------------------------------------------------------- host ---
static const int ESRC[NRL] = {0, 0, 1, 0};
static const int EDST[NRL] = {0, 1, 0, 2};

extern "C" void kernel_launch(void* const* d_in, const int* in_sizes, int n_in,
                              void* d_out, int out_size, void* d_ws, size_t ws_size,
                              hipStream_t stream) {
  const float* x[3] = {(const float*)d_in[0], (const float*)d_in[1], (const float*)d_in[2]};
  const float* lin_w = (const float*)d_in[4];
  const float* lin_b = (const float*)d_in[5];
  const float* k_w   = (const float*)d_in[6];
  const float* k_b   = (const float*)d_in[7];
  const float* q_w   = (const float*)d_in[8];
  const float* q_b   = (const float*)d_in[9];
  const float* v_w   = (const float*)d_in[10];
  const float* v_b   = (const float*)d_in[11];
  const float* a_w   = (const float*)d_in[12];
  const float* a_b   = (const float*)d_in[13];
  const float* skip  = (const float*)d_in[14];
  const float* a_rel = (const float*)d_in[15];
  const float* m_rel = (const float*)d_in[16];
  const float* p_rel = (const float*)d_in[17];
  const int* edge_index = (const int*)d_in[18];
  const int* ntype   = (const int*)d_in[19];
  float* out = (float*)d_out;

  const size_t NF = (size_t)NT_NODES * FDIM;
  float* p = (float*)d_ws;
  auto alloc = [&](size_t n) { float* r = p; p += n; return r; };
  float* bufA = alloc(3 * NF);                    // h ping (bf16; f32 after final layer)
  float* bufB = alloc(3 * NF);                    // h pong / bf16 Q' scratch (4 tables)
  u16* aggb = (u16*)alloc(3 * NF / 2);            // bf16 agg, rels 0,1,3
  u16* aggXb = (u16*)alloc(NF / 2);               // bf16 agg, rel 2
  u16* kv0 = (u16*)alloc(NF);                     // KV pair-interleaved, src type 0 [N][256]
  u16* kv1 = (u16*)alloc(NF);                     // KV pair-interleaved, src type 1
  u16* wt  = (u16*)alloc(23 * FDIM * FDIM / 2);   // 23 bf16 W^T matrices
  u16* wqp = (u16*)alloc(8 * FDIM * FDIM / 2);    // 8 fused Q' weights (bf16 W^T)
  float* bqp = alloc(8 * FDIM);                   // 8 fused Q' biases
  int* counts  = (int*)(p);
  int* cursor  = counts + NRL * NT_NODES;
  int* offsets = cursor + NRL * NT_NODES;
  int* aux     = offsets + NRL * (NT_NODES + 1);
  int* auxe    = aux + NRL * SCAN_BLOCKS;
  int* csr_src = auxe + NRL * SCAN_BLOCKS;        // [4][E] + 8 slack

  const int gemm_gx = (NT_NODES + 63) / 64;   // 469

  // ---- weight prep: bf16 W^T (QKV 14, lin 3, a_w 6) + fused Q' ----
  {
    WtBatch wb{};
    for (int l = 0; l < NLY; l++) {
      for (int t = 0; t < 3; t++)
        wb.w[l * 7 + t] = q_w + (size_t)(l * NTY + t) * FDIM * FDIM;
      wb.w[l * 7 + 3] = k_w + (size_t)(l * NTY + 0) * FDIM * FDIM;
      wb.w[l * 7 + 4] = v_w + (size_t)(l * NTY + 0) * FDIM * FDIM;
      wb.w[l * 7 + 5] = k_w + (size_t)(l * NTY + 1) * FDIM * FDIM;
      wb.w[l * 7 + 6] = v_w + (size_t)(l * NTY + 1) * FDIM * FDIM;
    }
    for (int t = 0; t < 3; t++)
      wb.w[14 + t] = lin_w + (size_t)t * FDIM * FDIM;
    for (int l = 0; l < NLY; l++)
      for (int t = 0; t < 3; t++)
        wb.w[17 + l * 3 + t] = a_w + (size_t)(l * NTY + t) * FDIM * FDIM;
    wt_prep<<<dim3(23), 256, 0, stream>>>(wb, wt);
    qfuse<<<dim3(NLY * NRL), 256, 0, stream>>>(q_w, q_b, a_rel, p_rel, wqp, bqp);
  }

  // ---- CSR build ----
  hipMemsetAsync(counts, 0, NRL * NT_NODES * sizeof(int), stream);
  csr_hist<<<dim3((NRL * NE_EDGES + 255) / 256), 256, 0, stream>>>(edge_index, counts);
  scan_block<<<dim3(SCAN_BLOCKS, NRL), 256, 0, stream>>>(counts, offsets, aux);
  scan_aux<<<dim3(NRL), 128, 0, stream>>>(aux, auxe, offsets);
  scan_add<<<dim3(SCAN_BLOCKS, NRL), 256, 0, stream>>>(auxe, offsets, cursor);
  csr_scatter<<<dim3((NRL * NE_EDGES + 255) / 256), 256, 0, stream>>>(edge_index, cursor, csr_src);
  csr_pad<<<dim3(1), 64, 0, stream>>>(csr_src + (size_t)NRL * NE_EDGES);

  // input projection: h[t] = relu(x_t @ lin_w[t] + lin_b[t])  (MFMA, bf16 out)
  {
    GemmBatchF gb{};
    for (int t = 0; t < 3; t++) {
      gb.t[t].A = x[t];
      gb.t[t].A2 = nullptr;
      gb.t[t].WT = wt + (size_t)(14 + t) * FDIM * FDIM;
      gb.t[t].bias = lin_b + (size_t)t * FDIM;
      gb.t[t].C = (float*)((u16*)bufA + (size_t)t * NF);
      gb.t[t].oldh = nullptr; gb.t[t].skipp = nullptr;
    }
    gemm_mfma_f<0, 0, 1, 1, 0><<<dim3(gemm_gx, 1, 3), 256, 0, stream>>>(gb, NT_NODES);
  }

  float* cur = bufA;   // bf16 h
  float* alt = bufB;
  for (int l = 0; l < NLY; l++) {
    u16* qbf = (u16*)alt;            // 4 per-rel Q' tables (4*NF u16 <= alt)
    const u16* hb = (const u16*)cur;

    // fused QKV: 4 balanced z-slices (<=3 matmul passes each)
    {
      QkvBatch gb{};
      // z0: A=h0 -> Q'_r0 + paired K0/V0
      gb.t[0].A = hb;  gb.t[0].nplain = 1;
      gb.t[0].o[0] = { wqp + (size_t)(l * 4 + 0) * FDIM * FDIM, bqp + (size_t)(l * 4 + 0) * FDIM, qbf + 0 * NF };
      gb.t[0].haskv = 1;
      gb.t[0].WTk = wt + (size_t)(l * 7 + 3) * FDIM * FDIM;
      gb.t[0].biask = k_b + (size_t)(l * NTY + 0) * FDIM;
      gb.t[0].WTv = wt + (size_t)(l * 7 + 4) * FDIM * FDIM;
      gb.t[0].biasv = v_b + (size_t)(l * NTY + 0) * FDIM;
      gb.t[0].Ckv = (u32*)kv0;
      // z1: A=h1 -> Q'_r1 + paired K1/V1
      gb.t[1].A = hb + NF;  gb.t[1].nplain = 1;
      gb.t[1].o[0] = { wqp + (size_t)(l * 4 + 1) * FDIM * FDIM, bqp + (size_t)(l * 4 + 1) * FDIM, qbf + 1 * NF };
      gb.t[1].haskv = 1;
      gb.t[1].WTk = wt + (size_t)(l * 7 + 5) * FDIM * FDIM;
      gb.t[1].biask = k_b + (size_t)(l * NTY + 1) * FDIM;
      gb.t[1].WTv = wt + (size_t)(l * 7 + 6) * FDIM * FDIM;
      gb.t[1].biasv = v_b + (size_t)(l * NTY + 1) * FDIM;
      gb.t[1].Ckv = (u32*)kv1;
      // z2: A=h2 -> Q'_r3
      gb.t[2].A = hb + 2 * NF;  gb.t[2].nplain = 1;
      gb.t[2].o[0] = { wqp + (size_t)(l * 4 + 3) * FDIM * FDIM, bqp + (size_t)(l * 4 + 3) * FDIM, qbf + 3 * NF };
      gb.t[2].haskv = 0;
      // z3: A=h0 (re-staged) -> Q'_r2
      gb.t[3].A = hb;  gb.t[3].nplain = 1;
      gb.t[3].o[0] = { wqp + (size_t)(l * 4 + 2) * FDIM * FDIM, bqp + (size_t)(l * 4 + 2) * FDIM, qbf + 2 * NF };
      gb.t[3].haskv = 0;
      gemm_qkv<<<dim3(gemm_gx, 1, 4), 256, 0, stream>>>(gb, NT_NODES);
    }

    // attention: all 4 relations, one launch; 2 waves per (node, relation)
    {
      AttnBatch ab{};
      for (int r = 0; r < NRL; r++) {
        ab.r[r].csr_src = csr_src + (size_t)r * NE_EDGES;
        ab.r[r].off  = offsets + (size_t)r * (NT_NODES + 1);
        ab.r[r].q    = qbf + (size_t)r * NF;          // per-relation Q' table
        ab.r[r].kv   = (ESRC[r] == 0) ? kv0 : kv1;
        ab.r[r].Mrel = m_rel + (size_t)(l * NRL + r) * NH * HD * HD;
        ab.r[r].agg  = (r == 2) ? aggXb : (aggb + (size_t)EDST[r] * NF);
      }
      attn_fused<<<dim3((NT_NODES + 1) / 2, NRL), 256, 0, stream>>>(ab);
    }

    // out: h_new[t] = a_s*(gelu(agg[t] [+aggX]) @ a_w + a_b) + (1-a_s)*h[t]
    // agg is bf16 (BF16_A); layer 0 -> bf16 h; final layer -> f32 h
    {
      GemmBatchF gb{};
      for (int t = 0; t < 3; t++) {
        gb.t[t].A = (const float*)(aggb + (size_t)t * NF);
        gb.t[t].A2 = (t == 0) ? (const float*)aggXb : nullptr;
        gb.t[t].WT = wt + (size_t)(17 + l * 3 + t) * FDIM * FDIM;
        gb.t[t].bias = a_b + (size_t)(l * NTY + t) * FDIM;
        gb.t[t].oldh = hb + (size_t)t * NF;
        gb.t[t].skipp = skip + (size_t)(l * NTY + t);
        if (l == 0) gb.t[t].C = (float*)((u16*)alt + (size_t)t * NF);
        else        gb.t[t].C = alt + (size_t)t * NF;
      }
      if (l == 0) gemm_mfma_f<1, 1, 0, 1, 1><<<dim3(gemm_gx, 1, 3), 256, 0, stream>>>(gb, NT_NODES);
      else        gemm_mfma_f<1, 1, 0, 0, 1><<<dim3(gemm_gx, 1, 3), 256, 0, stream>>>(gb, NT_NODES);
    }
    float* tmp = cur; cur = alt; alt = tmp;
  }

  const int NN = 3 * NT_NODES;
  scatter_out<<<dim3((NN * 32 + 255) / 256), 256, 0, stream>>>(
      cur, cur + NF, cur + 2 * NF, ntype, out, NN);
}

// Round 18
// 524.061 us; speedup vs baseline: 1.0186x; 1.0186x over previous
//
#include <hip/hip_runtime.h>
#include <math.h>

#define NT_NODES 30000
#define NE_EDGES 200000
#define NTY 3
#define NRL 4
#define NLY 2
#define NH 8
#define HD 16
#define FDIM 128
#define SCAN_BLOCKS 118   // ceil(30000/256)

typedef unsigned short u16;
typedef unsigned int u32;
typedef __attribute__((ext_vector_type(8))) short bf16x8;
typedef __attribute__((ext_vector_type(4))) float f32x4;

__device__ __forceinline__ float bf2f(u16 u) {
  return __uint_as_float(((u32)u) << 16);
}
__device__ __forceinline__ u16 f2bf(float f) {   // RNE
  u32 u = __float_as_uint(f);
  return (u16)((u + 0x7FFFu + ((u >> 16) & 1u)) >> 16);
}

__device__ __forceinline__ float gelu_f(float x) {
  return 0.5f * x * (1.f + erff(x * 0.7071067811865475f));
}

// -------------------------------------------------- weight prep (bf16 W^T) --
struct WtBatch { const float* w[23]; };
__global__ __launch_bounds__(256) void wt_prep(WtBatch wb, u16* wt) {
  const float* w = wb.w[blockIdx.x];
  u16* o = wt + (size_t)blockIdx.x * FDIM * FDIM;
  for (int i = threadIdx.x; i < FDIM * FDIM; i += 256) {
    int n = i >> 7, k = i & 127;            // o[n][k] = w[k][n]
    o[i] = f2bf(w[(size_t)k * FDIM + n]);
  }
}

// ---- fused Q' weights: per (layer, rel) WT'[n=h*16+cl][k] =
//      s_h * sum_ee A_rel[h][cl][ee] * q_w[dst(r)][k][h*16+ee]; s_h = prel/4.
__global__ __launch_bounds__(256) void qfuse(const float* __restrict__ q_w,
                                             const float* __restrict__ q_b,
                                             const float* __restrict__ a_rel,
                                             const float* __restrict__ p_rel,
                                             u16* __restrict__ wqp,
                                             float* __restrict__ bqp) {
  const int lr = blockIdx.x;            // 0..7 = l*4+r
  const int l = lr >> 2, r = lr & 3;
  const int dt = (r == 1) ? 1 : ((r == 3) ? 2 : 0);   // EDST
  const float* qw = q_w + (size_t)(l * NTY + dt) * FDIM * FDIM;
  const float* qb = q_b + (size_t)(l * NTY + dt) * FDIM;
  const float* A  = a_rel + (size_t)(l * NRL + r) * NH * HD * HD;
  const float* pr = p_rel + (size_t)(l * NRL + r) * NH;
  u16* wo = wqp + (size_t)lr * FDIM * FDIM;
  float* bo = bqp + (size_t)lr * FDIM;

  __shared__ float As[NH * HD * HD];   // 8KB
  __shared__ float sh[NH];
  for (int i = threadIdx.x; i < NH * HD * HD; i += 256) As[i] = A[i];
  if (threadIdx.x < NH) sh[threadIdx.x] = pr[threadIdx.x] * 0.25f;
  __syncthreads();

  for (int i = threadIdx.x; i < FDIM * FDIM; i += 256) {
    int n = i >> 7, k = i & 127;
    int h = n >> 4, cl = n & 15;
    float s = 0.f;
    #pragma unroll
    for (int ee = 0; ee < HD; ee++)
      s += qw[(size_t)k * FDIM + h * HD + ee] * As[h * HD * HD + cl * HD + ee];
    wo[(size_t)n * FDIM + k] = f2bf(s * sh[h]);
  }
  if (threadIdx.x < FDIM) {
    int n = threadIdx.x, h = n >> 4, cl = n & 15;
    float s = 0.f;
    #pragma unroll
    for (int ee = 0; ee < HD; ee++)
      s += qb[h * HD + ee] * As[h * HD * HD + cl * HD + ee];
    bo[n] = s * sh[h];
  }
}

// ------------------------------------------------------- MFMA core ----------
// Block: 256 thr (4 waves), tile 64 rows; wave w -> cols 32w..32w+31.
// LDS XOR-swizzle on 16B granules: granule k8 stored at k8 ^ (row&7).
// C/D layout: col=lane&15, row=(lane>>4)*4+rr (verified R9).

// --- fused QKV: A (bf16 h) staged once, MFMA A-fragments in registers.
// Plain outputs (Q') write contiguous u16 rows. Optional KV pair: K-pass
// acc kept in regs, V-pass acc computed, then ONE coalesced u32 store per
// (row,col) = K | V<<16 into kv[row][col] (pair-interleaved table).
struct QkvOut { const u16* WT; const float* bias; u16* C; };
struct QkvTask {
  const u16* A; int nplain; QkvOut o[2];
  int haskv; const u16* WTk; const float* biask; const u16* WTv; const float* biasv; u32* Ckv;
};
struct QkvBatch { QkvTask t[3]; };

__global__ __launch_bounds__(256) void gemm_qkv(QkvBatch gb, int M) {
  const QkvTask tk = gb.t[blockIdx.z];
  const int tid = threadIdx.x;
  const int wv = tid >> 6;
  const int lane = tid & 63;
  const int row0 = blockIdx.x * 64;

  __shared__ u16 As[64 * 128];
  __shared__ u16 Bt[128 * 128];

  // stage A (bf16 direct copy, swizzled granules)
  #pragma unroll
  for (int i = 0; i < 4; i++) {
    int g = tid + 256 * i;
    int r = g >> 4, k8 = g & 15;
    int grow = row0 + r;
    uint4 v = make_uint4(0, 0, 0, 0);
    if (grow < M) v = *(const uint4*)(tk.A + (size_t)grow * FDIM + k8 * 8);
    *(uint4*)(As + r * 128 + ((k8 ^ (r & 7)) * 8)) = v;
  }
  __syncthreads();

  const int rsel = lane & 15, ksel = lane >> 4;
  // A-fragments in registers, reused for all outputs
  bf16x8 af[4][4];
  #pragma unroll
  for (int ks = 0; ks < 4; ks++) {
    int kg = ks * 4 + ksel;
    #pragma unroll
    for (int i = 0; i < 4; i++) {
      int r = 16 * i + rsel;
      af[ks][i] = *(const bf16x8*)(As + r * 128 + ((kg ^ (r & 7)) * 8));
    }
  }

  // ---- plain outputs (Q' tables, contiguous u16 writes) ----
  for (int ot = 0; ot < tk.nplain; ot++) {
    const QkvOut oo = tk.o[ot];
    #pragma unroll
    for (int i = 0; i < 8; i++) {
      int g = tid + 256 * i;
      int n = g >> 4, k8 = g & 15;
      uint4 v = *(const uint4*)(oo.WT + (size_t)n * FDIM + k8 * 8);
      *(uint4*)(Bt + n * 128 + ((k8 ^ (n & 7)) * 8)) = v;
    }
    __syncthreads();

    f32x4 acc[4][2] = {};
    #pragma unroll
    for (int ks = 0; ks < 4; ks++) {
      int kg = ks * 4 + ksel;
      bf16x8 bfr[2];
      #pragma unroll
      for (int j = 0; j < 2; j++) {
        int n = 32 * wv + 16 * j + rsel;
        bfr[j] = *(const bf16x8*)(Bt + n * 128 + ((kg ^ (n & 7)) * 8));
      }
      #pragma unroll
      for (int i = 0; i < 4; i++)
        #pragma unroll
        for (int j = 0; j < 2; j++)
          acc[i][j] = __builtin_amdgcn_mfma_f32_16x16x32_bf16(af[ks][i], bfr[j], acc[i][j], 0, 0, 0);
    }

    float bj[2];
    int colj[2];
    #pragma unroll
    for (int j = 0; j < 2; j++) {
      colj[j] = 32 * wv + 16 * j + rsel;
      bj[j] = oo.bias[colj[j]];
    }
    #pragma unroll
    for (int i = 0; i < 4; i++) {
      #pragma unroll
      for (int rr = 0; rr < 4; rr++) {
        int grow = row0 + 16 * i + (lane >> 4) * 4 + rr;
        if (grow >= M) continue;
        #pragma unroll
        for (int j = 0; j < 2; j++)
          oo.C[(size_t)grow * FDIM + colj[j]] = f2bf(acc[i][j][rr] + bj[j]);
      }
    }
    __syncthreads();
  }

  // ---- KV pair: K-pass acc held in regs, V-pass, then coalesced u32 write --
  if (tk.haskv) {
    // K pass
    #pragma unroll
    for (int i = 0; i < 8; i++) {
      int g = tid + 256 * i;
      int n = g >> 4, k8 = g & 15;
      uint4 v = *(const uint4*)(tk.WTk + (size_t)n * FDIM + k8 * 8);
      *(uint4*)(Bt + n * 128 + ((k8 ^ (n & 7)) * 8)) = v;
    }
    __syncthreads();
    f32x4 accK[4][2] = {};
    #pragma unroll
    for (int ks = 0; ks < 4; ks++) {
      int kg = ks * 4 + ksel;
      bf16x8 bfr[2];
      #pragma unroll
      for (int j = 0; j < 2; j++) {
        int n = 32 * wv + 16 * j + rsel;
        bfr[j] = *(const bf16x8*)(Bt + n * 128 + ((kg ^ (n & 7)) * 8));
      }
      #pragma unroll
      for (int i = 0; i < 4; i++)
        #pragma unroll
        for (int j = 0; j < 2; j++)
          accK[i][j] = __builtin_amdgcn_mfma_f32_16x16x32_bf16(af[ks][i], bfr[j], accK[i][j], 0, 0, 0);
    }
    __syncthreads();
    // V pass
    #pragma unroll
    for (int i = 0; i < 8; i++) {
      int g = tid + 256 * i;
      int n = g >> 4, k8 = g & 15;
      uint4 v = *(const uint4*)(tk.WTv + (size_t)n * FDIM + k8 * 8);
      *(uint4*)(Bt + n * 128 + ((k8 ^ (n & 7)) * 8)) = v;
    }
    __syncthreads();
    f32x4 accV[4][2] = {};
    #pragma unroll
    for (int ks = 0; ks < 4; ks++) {
      int kg = ks * 4 + ksel;
      bf16x8 bfr[2];
      #pragma unroll
      for (int j = 0; j < 2; j++) {
        int n = 32 * wv + 16 * j + rsel;
        bfr[j] = *(const bf16x8*)(Bt + n * 128 + ((kg ^ (n & 7)) * 8));
      }
      #pragma unroll
      for (int i = 0; i < 4; i++)
        #pragma unroll
        for (int j = 0; j < 2; j++)
          accV[i][j] = __builtin_amdgcn_mfma_f32_16x16x32_bf16(af[ks][i], bfr[j], accV[i][j], 0, 0, 0);
    }

    float bk[2], bv[2];
    int colj[2];
    #pragma unroll
    for (int j = 0; j < 2; j++) {
      colj[j] = 32 * wv + 16 * j + rsel;
      bk[j] = tk.biask[colj[j]];
      bv[j] = tk.biasv[colj[j]];
    }
    #pragma unroll
    for (int i = 0; i < 4; i++) {
      #pragma unroll
      for (int rr = 0; rr < 4; rr++) {
        int grow = row0 + 16 * i + (lane >> 4) * 4 + rr;
        if (grow >= M) continue;
        #pragma unroll
        for (int j = 0; j < 2; j++) {
          u32 pk = (u32)f2bf(accK[i][j][rr] + bk[j]);
          u32 pv = (u32)f2bf(accV[i][j][rr] + bv[j]);
          tk.Ckv[(size_t)grow * FDIM + colj[j]] = pk | (pv << 16);
        }
      }
    }
  }
}

// --- f32-A variant (in-proj RELU / out-GEMM gelu+skip). oldh is bf16.
struct GemmTaskF {
  const float* A; const float* A2; const u16* WT; const float* bias;
  float* C; const u16* oldh; const float* skipp;
};
struct GemmBatchF { GemmTaskF t[3]; };

template<int GELU_A, int EPI_SKIP, int RELU, int BF16_OUT>
__global__ __launch_bounds__(256) void gemm_mfma_f(GemmBatchF gb, int M) {
  const GemmTaskF tk = gb.t[blockIdx.z];
  const int tid = threadIdx.x;
  const int wv = tid >> 6;
  const int lane = tid & 63;
  const int row0 = blockIdx.x * 64;

  __shared__ u16 As[64 * 128];
  __shared__ u16 Bt[128 * 128];

  #pragma unroll
  for (int i = 0; i < 4; i++) {
    int g = tid + 256 * i;
    int r = g >> 4, k8 = g & 15;
    int grow = row0 + r;
    float4 va = make_float4(0.f, 0.f, 0.f, 0.f), vb = va;
    if (grow < M) {
      const float* ap = tk.A + (size_t)grow * FDIM + k8 * 8;
      va = *(const float4*)ap;
      vb = *(const float4*)(ap + 4);
      if (GELU_A && tk.A2) {
        const float* ap2 = tk.A2 + (size_t)grow * FDIM + k8 * 8;
        float4 w = *(const float4*)ap2;
        float4 z = *(const float4*)(ap2 + 4);
        va.x += w.x; va.y += w.y; va.z += w.z; va.w += w.w;
        vb.x += z.x; vb.y += z.y; vb.z += z.z; vb.w += z.w;
      }
      if (GELU_A) {
        va.x = gelu_f(va.x); va.y = gelu_f(va.y); va.z = gelu_f(va.z); va.w = gelu_f(va.w);
        vb.x = gelu_f(vb.x); vb.y = gelu_f(vb.y); vb.z = gelu_f(vb.z); vb.w = gelu_f(vb.w);
      }
    }
    u32 w0 = (u32)f2bf(va.x) | ((u32)f2bf(va.y) << 16);
    u32 w1 = (u32)f2bf(va.z) | ((u32)f2bf(va.w) << 16);
    u32 w2 = (u32)f2bf(vb.x) | ((u32)f2bf(vb.y) << 16);
    u32 w3 = (u32)f2bf(vb.z) | ((u32)f2bf(vb.w) << 16);
    u32* dst = (u32*)(As + r * 128 + ((k8 ^ (r & 7)) * 8));
    dst[0] = w0; dst[1] = w1; dst[2] = w2; dst[3] = w3;
  }
  #pragma unroll
  for (int i = 0; i < 8; i++) {
    int g = tid + 256 * i;
    int n = g >> 4, k8 = g & 15;
    uint4 v = *(const uint4*)(tk.WT + (size_t)n * FDIM + k8 * 8);
    *(uint4*)(Bt + n * 128 + ((k8 ^ (n & 7)) * 8)) = v;
  }
  __syncthreads();

  f32x4 acc[4][2] = {};
  const int rsel = lane & 15, ksel = lane >> 4;
  #pragma unroll
  for (int ks = 0; ks < 4; ks++) {
    int kg = ks * 4 + ksel;
    bf16x8 af[4], bfr[2];
    #pragma unroll
    for (int i = 0; i < 4; i++) {
      int r = 16 * i + rsel;
      af[i] = *(const bf16x8*)(As + r * 128 + ((kg ^ (r & 7)) * 8));
    }
    #pragma unroll
    for (int j = 0; j < 2; j++) {
      int n = 32 * wv + 16 * j + rsel;
      bfr[j] = *(const bf16x8*)(Bt + n * 128 + ((kg ^ (n & 7)) * 8));
    }
    #pragma unroll
    for (int i = 0; i < 4; i++)
      #pragma unroll
      for (int j = 0; j < 2; j++)
        acc[i][j] = __builtin_amdgcn_mfma_f32_16x16x32_bf16(af[i], bfr[j], acc[i][j], 0, 0, 0);
  }

  float a_s = 0.f, b_s = 0.f;
  if (EPI_SKIP) { a_s = 1.f / (1.f + expf(-tk.skipp[0])); b_s = 1.f - a_s; }
  float bj[2];
  int colj[2];
  #pragma unroll
  for (int j = 0; j < 2; j++) {
    colj[j] = 32 * wv + 16 * j + rsel;
    bj[j] = tk.bias[colj[j]];
  }
  #pragma unroll
  for (int i = 0; i < 4; i++) {
    #pragma unroll
    for (int rr = 0; rr < 4; rr++) {
      int grow = row0 + 16 * i + (lane >> 4) * 4 + rr;
      if (grow >= M) continue;
      #pragma unroll
      for (int j = 0; j < 2; j++) {
        float v = acc[i][j][rr] + bj[j];
        if (RELU) v = fmaxf(v, 0.f);
        if (EPI_SKIP) v = a_s * v + b_s * bf2f(tk.oldh[(size_t)grow * FDIM + colj[j]]);
        if (BF16_OUT) ((u16*)tk.C)[(size_t)grow * FDIM + colj[j]] = f2bf(v);
        else tk.C[(size_t)grow * FDIM + colj[j]] = v;
      }
    }
  }
}

// ------------------------------------------------------------- CSR build ----
__global__ __launch_bounds__(256) void csr_hist(const int* __restrict__ edge_index,
                                                int* __restrict__ counts) {
  int idx = blockIdx.x * 256 + threadIdx.x;
  if (idx >= NRL * NE_EDGES) return;
  int r = idx / NE_EDGES, e = idx - r * NE_EDGES;
  int d = edge_index[(size_t)(r * 2 + 1) * NE_EDGES + e];
  atomicAdd(&counts[r * NT_NODES + d], 1);
}

__global__ __launch_bounds__(256) void scan_block(const int* __restrict__ counts,
                                                  int* __restrict__ off,
                                                  int* __restrict__ aux) {
  int r = blockIdx.y, b = blockIdx.x, t = threadIdx.x;
  int i = b * 256 + t;
  int v = (i < NT_NODES) ? counts[r * NT_NODES + i] : 0;
  __shared__ int lds[256];
  lds[t] = v;
  __syncthreads();
  #pragma unroll
  for (int dlt = 1; dlt < 256; dlt <<= 1) {
    int x = (t >= dlt) ? lds[t - dlt] : 0;
    __syncthreads();
    lds[t] += x;
    __syncthreads();
  }
  if (i < NT_NODES) off[(size_t)r * (NT_NODES + 1) + i] = lds[t] - v;
  if (t == 255) aux[r * SCAN_BLOCKS + b] = lds[255];
}

__global__ __launch_bounds__(128) void scan_aux(const int* __restrict__ aux,
                                                int* __restrict__ auxe,
                                                int* __restrict__ off) {
  int r = blockIdx.x, t = threadIdx.x;
  __shared__ int lds[128];
  int v = (t < SCAN_BLOCKS) ? aux[r * SCAN_BLOCKS + t] : 0;
  lds[t] = v;
  __syncthreads();
  #pragma unroll
  for (int dlt = 1; dlt < 128; dlt <<= 1) {
    int x = (t >= dlt) ? lds[t - dlt] : 0;
    __syncthreads();
    lds[t] += x;
    __syncthreads();
  }
  if (t < SCAN_BLOCKS) auxe[r * SCAN_BLOCKS + t] = lds[t] - v;
  if (t == 127) off[(size_t)r * (NT_NODES + 1) + NT_NODES] = lds[127];
}

__global__ __launch_bounds__(256) void scan_add(const int* __restrict__ auxe,
                                                int* __restrict__ off,
                                                int* __restrict__ cursor) {
  int r = blockIdx.y, b = blockIdx.x, t = threadIdx.x;
  int i = b * 256 + t;
  if (i >= NT_NODES) return;
  int val = off[(size_t)r * (NT_NODES + 1) + i] + auxe[r * SCAN_BLOCKS + b];
  off[(size_t)r * (NT_NODES + 1) + i] = val;
  cursor[r * NT_NODES + i] = val;
}

__global__ __launch_bounds__(256) void csr_scatter(const int* __restrict__ edge_index,
                                                   int* __restrict__ cursor,
                                                   int* __restrict__ csr_src) {
  int idx = blockIdx.x * 256 + threadIdx.x;
  if (idx >= NRL * NE_EDGES) return;
  int r = idx / NE_EDGES, e = idx - r * NE_EDGES;
  int s = edge_index[(size_t)(r * 2 + 0) * NE_EDGES + e];
  int d = edge_index[(size_t)(r * 2 + 1) * NE_EDGES + e];
  int pos = atomicAdd(&cursor[r * NT_NODES + d], 1);
  csr_src[(size_t)r * NE_EDGES + pos] = s;
}

__global__ void csr_pad(int* __restrict__ pad) {
  if (threadIdx.x < 8) pad[threadIdx.x] = 0;
}

// ---------------------------------------------------- fused attention -------
// HEAD-SPLIT + PRE-FUSED Q' + PAIR-INTERLEAVED KV (R16 structure):
// lane owns one channel; its (K,V) pair is one u32 gather per edge.
struct AttnRel {
  const int* csr_src; const int* off;
  const u16* q;        // bf16 Q' of this relation [N,128] (pre-transformed)
  const u16* kv;       // bf16 KV pair-interleaved [N,256]: K[c] low, V[c] high
  const float* Mrel;   // [8][16][16]
  float* agg;          // output [N,128] (overwritten)
};
struct AttnBatch { AttnRel r[4]; };

__global__ __launch_bounds__(256) void attn_fused(AttnBatch ab) {
  const AttnRel rp = ab.r[blockIdx.y];
  const int wave = threadIdx.x >> 6;
  const int lane = threadIdx.x & 63;
  const int d = blockIdx.x * 2 + (wave >> 1);
  if (d >= NT_NODES) return;
  const int hf = wave & 1;              // half: channels hf*64 .. hf*64+63
  const int cl = lane & 15;             // channel within head
  const int gh = hf * 4 + (lane >> 4);  // global head 0..7
  const int grp = lane & ~15;           // 16-lane head group base
  const int el = lane & 7;              // edge slot in transposed reduce

  // ---- Q' already includes A_rel and p/4: direct load ----
  float qp = bf2f(rp.q[(size_t)d * FDIM + hf * 64 + lane]);

  const u32* KV = (const u32*)rp.kv;    // [N][128] u32 (K,V) pairs
  const int* __restrict__ cs = rp.csr_src;
  int lo = rp.off[d], hi = rp.off[d + 1];
  lo = __builtin_amdgcn_readfirstlane(lo);
  hi = __builtin_amdgcn_readfirstlane(hi);
  const size_t poff = hf * 64 + lane;   // u32 pair index within row
  float acc = 0.f, ssum = 0.f;
  for (int pos = lo; pos < hi; pos += 8) {
    int s0 = cs[pos + 0], s1 = cs[pos + 1], s2 = cs[pos + 2], s3 = cs[pos + 3];
    int s4 = cs[pos + 4], s5 = cs[pos + 5], s6 = cs[pos + 6], s7 = cs[pos + 7];
    u32 w0 = KV[(size_t)s0 * 128 + poff], w1 = KV[(size_t)s1 * 128 + poff];
    u32 w2 = KV[(size_t)s2 * 128 + poff], w3 = KV[(size_t)s3 * 128 + poff];
    u32 w4 = KV[(size_t)s4 * 128 + poff], w5 = KV[(size_t)s5 * 128 + poff];
    u32 w6 = KV[(size_t)s6 * 128 + poff], w7 = KV[(size_t)s7 * 128 + poff];
    float p0 = qp * __uint_as_float(w0 << 16), p1 = qp * __uint_as_float(w1 << 16);
    float p2 = qp * __uint_as_float(w2 << 16), p3 = qp * __uint_as_float(w3 << 16);
    float p4 = qp * __uint_as_float(w4 << 16), p5 = qp * __uint_as_float(w5 << 16);
    float p6 = qp * __uint_as_float(w6 << 16), p7 = qp * __uint_as_float(w7 << 16);
    // transposed butterfly over 8 lanes, then fold the other 8 of the head
    float s01 = (lane & 1) ? p0 : p1, c01 = (lane & 1) ? p1 : p0;
    float s23 = (lane & 1) ? p2 : p3, c23 = (lane & 1) ? p3 : p2;
    float s45 = (lane & 1) ? p4 : p5, c45 = (lane & 1) ? p5 : p4;
    float s67 = (lane & 1) ? p6 : p7, c67 = (lane & 1) ? p7 : p6;
    float r01 = c01 + __shfl_xor(s01, 1, 64);
    float r23 = c23 + __shfl_xor(s23, 1, 64);
    float r45 = c45 + __shfl_xor(s45, 1, 64);
    float r67 = c67 + __shfl_xor(s67, 1, 64);
    float sA = (lane & 2) ? r01 : r23, cA = (lane & 2) ? r23 : r01;
    float sB = (lane & 2) ? r45 : r67, cB = (lane & 2) ? r67 : r45;
    float rA = cA + __shfl_xor(sA, 2, 64);
    float rB = cB + __shfl_xor(sB, 2, 64);
    float sC = (lane & 4) ? rA : rB, cC = (lane & 4) ? rB : rA;
    float rF = cC + __shfl_xor(sC, 4, 64);
    rF += __shfl_xor(rF, 8, 64);     // fold remaining 8 lanes of the head
    int rem = hi - pos;              // scalar
    float e = (el < rem) ? __expf(rF) : 0.f;
    float e0 = __shfl(e, grp + 0, 64), e1 = __shfl(e, grp + 1, 64);
    float e2 = __shfl(e, grp + 2, 64), e3 = __shfl(e, grp + 3, 64);
    float e4 = __shfl(e, grp + 4, 64), e5 = __shfl(e, grp + 5, 64);
    float e6 = __shfl(e, grp + 6, 64), e7 = __shfl(e, grp + 7, 64);
    acc += e0 * __uint_as_float(w0 & 0xFFFF0000u) + e1 * __uint_as_float(w1 & 0xFFFF0000u)
         + e2 * __uint_as_float(w2 & 0xFFFF0000u) + e3 * __uint_as_float(w3 & 0xFFFF0000u)
         + e4 * __uint_as_float(w4 & 0xFFFF0000u) + e5 * __uint_as_float(w5 & 0xFFFF0000u)
         + e6 * __uint_as_float(w6 & 0xFFFF0000u) + e7 * __uint_as_float(w7 & 0xFFFF0000u);
    ssum += ((e0 + e1) + (e2 + e3)) + ((e4 + e5) + (e6 + e7));
  }
  float inv = 1.f / (ssum + 1e-16f);
  float S = acc * inv;   // lane's channel of the raw-V aggregate

  // ---- apply M_rel: out_cl = sum_d2 S[d2] * M[gh][d2][cl] ----
  const float* M = rp.Mrel + (size_t)gh * 256;
  float o = 0.f;
  #pragma unroll
  for (int d2 = 0; d2 < 16; d2++) {
    float sv = __shfl(S, grp + d2, 64);
    o += sv * M[d2 * 16 + cl];
  }
  rp.agg[(size_t)d * FDIM + hf * 64 + lane] = o;
}

// ---------------------------------------------------------------- scatter ---
__global__ __launch_bounds__(256) void scatter_out(const float* h0, const float* h1,
                                                   const float* h2, const int* ntype,
                                                   float* out, int NN) {
  int idx = blockIdx.x * 256 + threadIdx.x;
  if (idx >= NN * 32) return;
  int i = idx >> 5, c4 = idx & 31;
  int t = ntype[i];
  const float* hp = (t == 0) ? h0 : ((t == 1) ? h1 : h2);
  int local = i - t * NT_NODES;
  ((float4*)out)[idx] = ((const float4*)hp)[(size_t)local * 32 + c4];
}

// ------------------------------------------------------------------- host ---
static const int ESRC[NRL] = {0, 0, 1, 0};
static const int EDST[NRL] = {0, 1, 0, 2};

extern "C" void kernel_launch(void* const* d_in, const int* in_sizes, int n_in,
                              void* d_out, int out_size, void* d_ws, size_t ws_size,
                              hipStream_t stream) {
  const float* x[3] = {(const float*)d_in[0], (const float*)d_in[1], (const float*)d_in[2]};
  const float* lin_w = (const float*)d_in[4];
  const float* lin_b = (const float*)d_in[5];
  const float* k_w   = (const float*)d_in[6];
  const float* k_b   = (const float*)d_in[7];
  const float* q_w   = (const float*)d_in[8];
  const float* q_b   = (const float*)d_in[9];
  const float* v_w   = (const float*)d_in[10];
  const float* v_b   = (const float*)d_in[11];
  const float* a_w   = (const float*)d_in[12];
  const float* a_b   = (const float*)d_in[13];
  const float* skip  = (const float*)d_in[14];
  const float* a_rel = (const float*)d_in[15];
  const float* m_rel = (const float*)d_in[16];
  const float* p_rel = (const float*)d_in[17];
  const int* edge_index = (const int*)d_in[18];
  const int* ntype   = (const int*)d_in[19];
  float* out = (float*)d_out;

  const size_t NF = (size_t)NT_NODES * FDIM;
  float* p = (float*)d_ws;
  auto alloc = [&](size_t n) { float* r = p; p += n; return r; };
  float* bufA = alloc(3 * NF);                    // h ping (bf16; f32 after final layer)
  float* bufB = alloc(3 * NF);                    // h pong / bf16 Q' scratch (4 tables)
  float* agg  = alloc(3 * NF);                    // rels 0,1,3
  float* aggX = alloc(NF);                        // rel 2 (summed in out-GEMM)
  u16* kv0 = (u16*)alloc(NF);                     // KV pair-interleaved, src type 0 [N][256]
  u16* kv1 = (u16*)alloc(NF);                     // KV pair-interleaved, src type 1
  u16* wt  = (u16*)alloc(23 * FDIM * FDIM / 2);   // 23 bf16 W^T matrices
  u16* wqp = (u16*)alloc(8 * FDIM * FDIM / 2);    // 8 fused Q' weights (bf16 W^T)
  float* bqp = alloc(8 * FDIM);                   // 8 fused Q' biases
  int* counts  = (int*)(p);
  int* cursor  = counts + NRL * NT_NODES;
  int* offsets = cursor + NRL * NT_NODES;
  int* aux     = offsets + NRL * (NT_NODES + 1);
  int* auxe    = aux + NRL * SCAN_BLOCKS;
  int* csr_src = auxe + NRL * SCAN_BLOCKS;        // [4][E] + 8 slack

  const int gemm_gx = (NT_NODES + 63) / 64;   // 469

  // ---- weight prep: bf16 W^T (QKV 14, lin 3, a_w 6) + fused Q' ----
  {
    WtBatch wb{};
    for (int l = 0; l < NLY; l++) {
      for (int t = 0; t < 3; t++)
        wb.w[l * 7 + t] = q_w + (size_t)(l * NTY + t) * FDIM * FDIM;
      wb.w[l * 7 + 3] = k_w + (size_t)(l * NTY + 0) * FDIM * FDIM;
      wb.w[l * 7 + 4] = v_w + (size_t)(l * NTY + 0) * FDIM * FDIM;
      wb.w[l * 7 + 5] = k_w + (size_t)(l * NTY + 1) * FDIM * FDIM;
      wb.w[l * 7 + 6] = v_w + (size_t)(l * NTY + 1) * FDIM * FDIM;
    }
    for (int t = 0; t < 3; t++)
      wb.w[14 + t] = lin_w + (size_t)t * FDIM * FDIM;
    for (int l = 0; l < NLY; l++)
      for (int t = 0; t < 3; t++)
        wb.w[17 + l * 3 + t] = a_w + (size_t)(l * NTY + t) * FDIM * FDIM;
    wt_prep<<<dim3(23), 256, 0, stream>>>(wb, wt);
    qfuse<<<dim3(NLY * NRL), 256, 0, stream>>>(q_w, q_b, a_rel, p_rel, wqp, bqp);
  }

  // ---- CSR build ----
  hipMemsetAsync(counts, 0, NRL * NT_NODES * sizeof(int), stream);
  csr_hist<<<dim3((NRL * NE_EDGES + 255) / 256), 256, 0, stream>>>(edge_index, counts);
  scan_block<<<dim3(SCAN_BLOCKS, NRL), 256, 0, stream>>>(counts, offsets, aux);
  scan_aux<<<dim3(NRL), 128, 0, stream>>>(aux, auxe, offsets);
  scan_add<<<dim3(SCAN_BLOCKS, NRL), 256, 0, stream>>>(auxe, offsets, cursor);
  csr_scatter<<<dim3((NRL * NE_EDGES + 255) / 256), 256, 0, stream>>>(edge_index, cursor, csr_src);
  csr_pad<<<dim3(1), 64, 0, stream>>>(csr_src + (size_t)NRL * NE_EDGES);

  // input projection: h[t] = relu(x_t @ lin_w[t] + lin_b[t])  (MFMA, bf16 out)
  {
    GemmBatchF gb{};
    for (int t = 0; t < 3; t++) {
      gb.t[t].A = x[t];
      gb.t[t].A2 = nullptr;
      gb.t[t].WT = wt + (size_t)(14 + t) * FDIM * FDIM;
      gb.t[t].bias = lin_b + (size_t)t * FDIM;
      gb.t[t].C = (float*)((u16*)bufA + (size_t)t * NF);
      gb.t[t].oldh = nullptr; gb.t[t].skipp = nullptr;
    }
    gemm_mfma_f<0, 0, 1, 1><<<dim3(gemm_gx, 1, 3), 256, 0, stream>>>(gb, NT_NODES);
  }

  float* cur = bufA;   // bf16 h
  float* alt = bufB;
  for (int l = 0; l < NLY; l++) {
    u16* qbf = (u16*)alt;            // 4 per-rel Q' tables (4*NF u16 <= alt)
    const u16* hb = (const u16*)cur;

    // fused QKV: one A-stage per type; plain Q' outputs + paired K/V output
    {
      QkvBatch gb{};
      // type 0: Q'_r0, Q'_r2 plain; K0/V0 paired -> kv0
      gb.t[0].A = hb;  gb.t[0].nplain = 2;
      gb.t[0].o[0] = { wqp + (size_t)(l * 4 + 0) * FDIM * FDIM, bqp + (size_t)(l * 4 + 0) * FDIM, qbf + 0 * NF };
      gb.t[0].o[1] = { wqp + (size_t)(l * 4 + 2) * FDIM * FDIM, bqp + (size_t)(l * 4 + 2) * FDIM, qbf + 2 * NF };
      gb.t[0].haskv = 1;
      gb.t[0].WTk = wt + (size_t)(l * 7 + 3) * FDIM * FDIM;
      gb.t[0].biask = k_b + (size_t)(l * NTY + 0) * FDIM;
      gb.t[0].WTv = wt + (size_t)(l * 7 + 4) * FDIM * FDIM;
      gb.t[0].biasv = v_b + (size_t)(l * NTY + 0) * FDIM;
      gb.t[0].Ckv = (u32*)kv0;
      // type 1: Q'_r1 plain; K1/V1 paired -> kv1
      gb.t[1].A = hb + NF;  gb.t[1].nplain = 1;
      gb.t[1].o[0] = { wqp + (size_t)(l * 4 + 1) * FDIM * FDIM, bqp + (size_t)(l * 4 + 1) * FDIM, qbf + 1 * NF };
      gb.t[1].haskv = 1;
      gb.t[1].WTk = wt + (size_t)(l * 7 + 5) * FDIM * FDIM;
      gb.t[1].biask = k_b + (size_t)(l * NTY + 1) * FDIM;
      gb.t[1].WTv = wt + (size_t)(l * 7 + 6) * FDIM * FDIM;
      gb.t[1].biasv = v_b + (size_t)(l * NTY + 1) * FDIM;
      gb.t[1].Ckv = (u32*)kv1;
      // type 2: Q'_r3 only
      gb.t[2].A = hb + 2 * NF;  gb.t[2].nplain = 1;
      gb.t[2].o[0] = { wqp + (size_t)(l * 4 + 3) * FDIM * FDIM, bqp + (size_t)(l * 4 + 3) * FDIM, qbf + 3 * NF };
      gb.t[2].haskv = 0;
      gemm_qkv<<<dim3(gemm_gx, 1, 3), 256, 0, stream>>>(gb, NT_NODES);
    }

    // attention: all 4 relations, one launch; 2 waves per (node, relation)
    {
      AttnBatch ab{};
      for (int r = 0; r < NRL; r++) {
        ab.r[r].csr_src = csr_src + (size_t)r * NE_EDGES;
        ab.r[r].off  = offsets + (size_t)r * (NT_NODES + 1);
        ab.r[r].q    = qbf + (size_t)r * NF;          // per-relation Q' table
        ab.r[r].kv   = (ESRC[r] == 0) ? kv0 : kv1;
        ab.r[r].Mrel = m_rel + (size_t)(l * NRL + r) * NH * HD * HD;
        ab.r[r].agg  = (r == 2) ? aggX : (agg + (size_t)EDST[r] * NF);
      }
      attn_fused<<<dim3((NT_NODES + 1) / 2, NRL), 256, 0, stream>>>(ab);
    }

    // out: h_new[t] = a_s*(gelu(agg[t] [+aggX]) @ a_w + a_b) + (1-a_s)*h[t]
    // layer 0 -> bf16 h; final layer -> f32 h (scatter needs full precision)
    {
      GemmBatchF gb{};
      for (int t = 0; t < 3; t++) {
        gb.t[t].A = agg + (size_t)t * NF;
        gb.t[t].A2 = (t == 0) ? aggX : nullptr;
        gb.t[t].WT = wt + (size_t)(17 + l * 3 + t) * FDIM * FDIM;
        gb.t[t].bias = a_b + (size_t)(l * NTY + t) * FDIM;
        gb.t[t].oldh = hb + (size_t)t * NF;
        gb.t[t].skipp = skip + (size_t)(l * NTY + t);
        if (l == 0) gb.t[t].C = (float*)((u16*)alt + (size_t)t * NF);
        else        gb.t[t].C = alt + (size_t)t * NF;
      }
      if (l == 0) gemm_mfma_f<1, 1, 0, 1><<<dim3(gemm_gx, 1, 3), 256, 0, stream>>>(gb, NT_NODES);
      else        gemm_mfma_f<1, 1, 0, 0><<<dim3(gemm_gx, 1, 3), 256, 0, stream>>>(gb, NT_NODES);
    }
    float* tmp = cur; cur = alt; alt = tmp;
  }

  const int NN = 3 * NT_NODES;
  scatter_out<<<dim3((NN * 32 + 255) / 256), 256, 0, stream>>>(
      cur, cur + NF, cur + 2 * NF, ntype, out, NN);
}